// Round 11
// baseline (221.925 us; speedup 1.0000x reference)
//
#include <hip/hip_runtime.h>
#include <hip/hip_fp16.h>
#include <cstdio>
#include <cstdint>

#define NREL 16
#define NBASE 8
#define NPB 512            // nodes per super-bin (bin = dst >> 9)
#define NPLACE 256         // histogram/place blocks
// Record packing: src[16:0] | et[20:17] | dlow[29:21]  (N <= 2^17)

typedef unsigned int uint;
typedef unsigned short ushort;

// ---------------------------------------------------------------------------
template <int CTRL>
__device__ __forceinline__ float dpp_add_f(float x) {
    int xi = __builtin_bit_cast(int, x);
    int yi = __builtin_amdgcn_update_dpp(0, xi, CTRL, 0xF, 0xF, true);
    return x + __builtin_bit_cast(float, yi);
}
__device__ __forceinline__ uint pk2(float lo, float hi) {
    __half2 t = __floats2half2_rn(lo, hi);
    return *(uint*)&t;
}
__device__ __forceinline__ float c16(uint v) {   // low 16 bits as fp16 -> f32
    ushort s = (ushort)v;
    return __half2float(*(const __half*)&s);
}

// ---------------------------------------------------------------------------
// k_fused1: three independent jobs, selected by block range:
//   [0, nb_pre)          node_pre (32 nodes/block): hcat = pack(fp16(h), fp16(h@A_w[0:32])),
//                        hA2 = h@A_w[32:64], curr = h@slw
//   [nb_pre, +64)        prep: Wcat16[k=i*8+b][o] = fp16(weight[b][i][o]); relA
//   [nb_pre+64, +NPLACE) hist2: per-(block,super-bin) LDS histogram of dst
// ---------------------------------------------------------------------------
__global__ __launch_bounds__(256) void k_fused1(
        const float* __restrict__ h, const float* __restrict__ A_w,
        const float* __restrict__ slw, const float* __restrict__ weight,
        const float* __restrict__ attn_emb, const float* __restrict__ A_b,
        const int* __restrict__ dst,
        uint* __restrict__ hcat, float* __restrict__ hA2, float* __restrict__ curr,
        __half* __restrict__ Wcat16, float* __restrict__ relA,
        int* __restrict__ histT,
        int N, int E, int nb_pre) {
    __shared__ __align__(16) float Wall[32 * 128];   // [i][c]: c<32 A1, <64 A2, <96 slw
    __shared__ float hbuf[32 * 33];
    __shared__ int hist[256];
    int bx = blockIdx.x;
    int t = threadIdx.x;
    if (bx < nb_pre) {
        // ---- node_pre: 32 nodes per block ----
        #pragma unroll
        for (int k = 0; k < 16; ++k) {
            int idx = t + 256 * k;
            int i = idx >> 7, c = idx & 127;
            float v = 0.f;
            if (c < 32)       v = A_w[i * 32 + c];
            else if (c < 64)  v = A_w[(32 + i) * 32 + (c - 32)];
            else if (c < 96)  v = slw[i * 32 + (c - 64)];
            Wall[idx] = v;
        }
        int n0 = bx * 32;
        #pragma unroll
        for (int k = 0; k < 4; ++k) {
            int idx = t + 256 * k;                   // 0..1023
            int row = idx >> 5, col = idx & 31;
            int n = n0 + row;
            hbuf[row * 33 + col] = (n < N) ? h[n * 32 + col] : 0.f;
        }
        __syncthreads();
        int nl = t >> 3;                             // node 0..31
        int tg = t & 7;                              // col-group 0..7 (12 cols)
        float4 a0 = {0,0,0,0}, a1 = {0,0,0,0}, a2 = {0,0,0,0};
        #pragma unroll 8
        for (int i = 0; i < 32; ++i) {
            float hv = hbuf[nl * 33 + i];
            float4 w0 = *(const float4*)&Wall[i * 128 + tg * 12];
            float4 w1 = *(const float4*)&Wall[i * 128 + tg * 12 + 4];
            float4 w2 = *(const float4*)&Wall[i * 128 + tg * 12 + 8];
            a0.x += hv * w0.x; a0.y += hv * w0.y; a0.z += hv * w0.z; a0.w += hv * w0.w;
            a1.x += hv * w1.x; a1.y += hv * w1.y; a1.z += hv * w1.z; a1.w += hv * w1.w;
            a2.x += hv * w2.x; a2.y += hv * w2.y; a2.z += hv * w2.z; a2.w += hv * w2.w;
        }
        int n = n0 + nl;
        if (n < N) {
            float4 acc[3] = {a0, a1, a2};
            #pragma unroll
            for (int j = 0; j < 3; ++j) {
                int c = tg * 12 + j * 4;
                if (c < 32) {
                    uint4 u;
                    u.x = pk2(hbuf[nl * 33 + c + 0], acc[j].x);
                    u.y = pk2(hbuf[nl * 33 + c + 1], acc[j].y);
                    u.z = pk2(hbuf[nl * 33 + c + 2], acc[j].z);
                    u.w = pk2(hbuf[nl * 33 + c + 3], acc[j].w);
                    *(uint4*)&hcat[(size_t)n * 32 + c] = u;
                } else if (c < 64) {
                    *(float4*)&hA2[n * 32 + (c - 32)] = acc[j];
                } else {
                    *(float4*)&curr[n * 32 + (c - 64)] = acc[j];
                }
            }
        }
    } else if (bx < nb_pre + 64) {
        // ---- prep ----
        int pidx = (bx - nb_pre) * 256 + t;          // 0..16383
        if (pidx < 8192) {
            int k = pidx >> 5, o = pidx & 31;
            int i = k >> 3, b = k & 7;
            Wcat16[pidx] = __float2half(weight[b * 1024 + i * 32 + o]);
        } else if (pidx < 8192 + 512) {
            int idx = pidx - 8192;
            int rr = idx >> 5, o = idx & 31;
            float a = A_b[o];
            #pragma unroll 8
            for (int i = 0; i < 32; ++i)
                a += attn_emb[rr * 32 + i] * A_w[(64 + i) * 32 + o];
            relA[idx] = a;
        }
    } else {
        // ---- hist2 ----
        int nsb = (N + NPB - 1) / NPB;
        hist[t] = 0;
        __syncthreads();
        int blk = bx - (nb_pre + 64);
        int bpb = (E + NPLACE - 1) / NPLACE;
        int e0 = blk * bpb;
        int e1 = e0 + bpb; if (e1 > E) e1 = E;
        for (int e = e0 + t; e < e1; e += 256)
            atomicAdd(&hist[dst[e] >> 9], 1);
        __syncthreads();
        if (t < nsb) histT[t * NPLACE + blk] = hist[t];
    }
}

// ---------------------------------------------------------------------------
// k_scanH: one block per super-bin. Exclusive scan over the bin's NPLACE
// block-counts (in place, bin-LOCAL); bin total -> binTot[bin].
// ---------------------------------------------------------------------------
__global__ __launch_bounds__(NPLACE) void k_scanH(int* __restrict__ histT,
        int* __restrict__ binTot) {
    __shared__ int sd[NPLACE];
    int bin = blockIdx.x, t = threadIdx.x;
    int v = histT[bin * NPLACE + t];
    sd[t] = v;
    __syncthreads();
    for (int off = 1; off < NPLACE; off <<= 1) {
        int x = (t >= off) ? sd[t - off] : 0;
        __syncthreads();
        sd[t] += x;
        __syncthreads();
    }
    histT[bin * NPLACE + t] = sd[t] - v;
    if (t == NPLACE - 1) binTot[bin] = sd[NPLACE - 1];
}

// ---------------------------------------------------------------------------
// k_scanB: single block exclusive-scans binTot in place (chunked);
// binTot[nsb] = total (= E).
// ---------------------------------------------------------------------------
__global__ __launch_bounds__(1024) void k_scanB(int* __restrict__ binTot, int nsb) {
    __shared__ int sd[1024];
    __shared__ int carry;
    int t = threadIdx.x;
    if (t == 0) carry = 0;
    __syncthreads();
    for (int base = 0; base < nsb; base += 1024) {
        int v = (base + t < nsb) ? binTot[base + t] : 0;
        sd[t] = v;
        __syncthreads();
        for (int off = 1; off < 1024; off <<= 1) {
            int x = (t >= off) ? sd[t - off] : 0;
            __syncthreads();
            sd[t] += x;
            __syncthreads();
        }
        int c = carry;
        if (base + t < nsb) binTot[base + t] = sd[t] - v + c;
        int tot = sd[1023];
        __syncthreads();
        if (t == 0) carry = c + tot;
        __syncthreads();
    }
    if (t == 0) binTot[nsb] = carry;
}

// ---------------------------------------------------------------------------
// k_place: LDS cursors = histT(bin-local) + binTot(bin base); each
// (block,bin) writes a contiguous run. LDS atomics only.
// ---------------------------------------------------------------------------
__global__ __launch_bounds__(256) void k_place(
        const int* __restrict__ src, const int* __restrict__ dst,
        const int* __restrict__ et,
        const int* __restrict__ histT, const int* __restrict__ binTot,
        int* __restrict__ tmp, int N, int E) {
    __shared__ int cur[256];
    int t = threadIdx.x;
    int nsb = (N + NPB - 1) / NPB;
    int blk = blockIdx.x;
    if (t < nsb) cur[t] = histT[t * NPLACE + blk] + binTot[t];
    __syncthreads();
    int bpb = (E + NPLACE - 1) / NPLACE;
    int e0 = blk * bpb;
    int e1 = e0 + bpb; if (e1 > E) e1 = E;
    for (int e = e0 + t; e < e1; e += 256) {
        int d = dst[e];
        int pos = atomicAdd(&cur[d >> 9], 1);
        tmp[pos] = src[e] | (et[e] << 17) | ((d & 511) << 21);
    }
}

// ---------------------------------------------------------------------------
// k_sortbin: one block per super-bin. Counts per-node degrees in LDS,
// block-scans -> writes rowptr + scale_s partial, then places records in
// exact per-node order.
// ---------------------------------------------------------------------------
__global__ __launch_bounds__(256) void k_sortbin(
        const int* __restrict__ tmp, int* __restrict__ packed,
        const int* __restrict__ binTot,
        int* __restrict__ rowptr, float* __restrict__ scale_s,
        int N, int E) {
    __shared__ int cnt[NPB];
    __shared__ int sa[256];
    __shared__ float sf[256];
    int t = threadIdx.x;
    int bin = blockIdx.x;
    int n0 = bin * NPB;
    cnt[t] = 0; cnt[t + 256] = 0;
    __syncthreads();
    int start = binTot[bin], end = binTot[bin + 1];
    for (int i = start + t; i < end; i += 256)
        atomicAdd(&cnt[(tmp[i] >> 21) & 511], 1);
    __syncthreads();
    int c0 = cnt[2 * t], c1 = cnt[2 * t + 1];
    sa[t] = c0 + c1;
    __syncthreads();
    for (int off = 1; off < 256; off <<= 1) {
        int x = (t >= off) ? sa[t - off] : 0;
        __syncthreads();
        sa[t] += x;
        __syncthreads();
    }
    int excl0 = sa[t] - (c0 + c1);
    int excl1 = excl0 + c0;
    int nA = n0 + 2 * t, nB = n0 + 2 * t + 1;
    if (nA <= N) rowptr[nA] = start + excl0;
    if (nB <= N) rowptr[nB] = start + excl1;
    float f = 0.f;
    if (nA < N) f += logf((float)c0 + 1.f);
    if (nB < N) f += logf((float)c1 + 1.f);
    sf[t] = f;
    __syncthreads();
    for (int s2 = 128; s2 > 0; s2 >>= 1) {
        if (t < s2) sf[t] += sf[t + s2];
        __syncthreads();
    }
    if (t == 0) atomicAdd(scale_s, sf[0]);
    cnt[2 * t] = start + excl0;
    cnt[2 * t + 1] = start + excl1;
    __syncthreads();
    for (int i = start + t; i < end; i += 256) {
        int rec = tmp[i];
        int dl = (rec >> 21) & 511;
        int pos = atomicAdd(&cnt[dl], 1);
        packed[pos] = rec;
    }
}

// ---------------------------------------------------------------------------
// k_node_agg: one node per 64-lane wave. Per edge: ONE 128B gather (hcat:
// packed h16+hA1), DPP attention reduce, then 8 basis-space FMAs
// (g[b] += a*hv*w_comp[r][b], wc from LDS). Writes g16[n][i][b] (fp16,
// pre-scaled by scale/deg). NO hrel table, no large random HBM reads.
// ---------------------------------------------------------------------------
__global__ __launch_bounds__(256) void k_node_agg(
        const uint* __restrict__ hcat, const float* __restrict__ hA2,
        const float* __restrict__ relA, const float* __restrict__ w_comp,
        const float* __restrict__ B_w, const float* __restrict__ B_b,
        const int* __restrict__ rowptr, const int* __restrict__ packed,
        const float* __restrict__ scale_s,
        uint* __restrict__ g16, int N) {
    __shared__ float relA_l[512];
    __shared__ __align__(16) float wcf[16 * 8];
    int t = threadIdx.x;
    relA_l[t] = relA[t];
    relA_l[t + 256] = relA[t + 256];
    if (t < 128) wcf[t] = w_comp[t];
    __syncthreads();
    int wave = t >> 6, t64 = t & 63, half = t64 >> 5, o = t64 & 31;
    int n = blockIdx.x * 4 + wave;
    if (n >= N) return;
    int r0 = rowptr[n], r1 = rowptr[n + 1];
    float zbase = hA2[n * 32 + o];
    float bwo = B_w[o], bb = B_b[0];
    float gb[8] = {0.f, 0.f, 0.f, 0.f, 0.f, 0.f, 0.f, 0.f};
    for (int c0 = r0; c0 < r1; c0 += 64) {
        int j = c0 + t64;
        int pk = (j < r1) ? packed[j] : 0;
        int m = r1 - c0; if (m > 64) m = 64;
        for (int k = 0; k < m; k += 4) {
            int idxA = k + half, idxB = k + 2 + half;
            int pkA = __shfl(pk, idxA, 64);
            int pkB = __shfl(pk, idxB, 64);
            int sA = pkA & 0x1FFFF, rA = (pkA >> 17) & 15;
            int sB = pkB & 0x1FFFF, rB = (pkB >> 17) & 15;
            uint wA = hcat[(size_t)sA * 32 + o];
            uint wB = hcat[(size_t)sB * 32 + o];
            float4 wcA0 = *(const float4*)&wcf[rA * 8];
            float4 wcA1 = *(const float4*)&wcf[rA * 8 + 4];
            float4 wcB0 = *(const float4*)&wcf[rB * 8];
            float4 wcB1 = *(const float4*)&wcf[rB * 8 + 4];
            float hvA = c16(wA), a1A = c16(wA >> 16);
            float hvB = c16(wB), a1B = c16(wB >> 16);
            float zA = a1A + zbase + relA_l[(rA << 5) + o];
            float zB = a1B + zbase + relA_l[(rB << 5) + o];
            float pA = fmaxf(zA, 0.f) * bwo;
            float pB = fmaxf(zB, 0.f) * bwo;
            pA = dpp_add_f<0x111>(pA); pB = dpp_add_f<0x111>(pB);
            pA = dpp_add_f<0x112>(pA); pB = dpp_add_f<0x112>(pB);
            pA = dpp_add_f<0x114>(pA); pB = dpp_add_f<0x114>(pB);
            pA = dpp_add_f<0x118>(pA); pB = dpp_add_f<0x118>(pB);
            pA = dpp_add_f<0x142>(pA); pB = dpp_add_f<0x142>(pB);
            pA = __shfl(pA, 31, 32) + bb;
            pB = __shfl(pB, 31, 32) + bb;
            float aA = 1.f / (1.f + __expf(-pA));
            float aB = 1.f / (1.f + __expf(-pB));
            float ahvA = (idxA < m) ? aA * hvA : 0.f;
            float ahvB = (idxB < m) ? aB * hvB : 0.f;
            gb[0] = fmaf(ahvA, wcA0.x, fmaf(ahvB, wcB0.x, gb[0]));
            gb[1] = fmaf(ahvA, wcA0.y, fmaf(ahvB, wcB0.y, gb[1]));
            gb[2] = fmaf(ahvA, wcA0.z, fmaf(ahvB, wcB0.z, gb[2]));
            gb[3] = fmaf(ahvA, wcA0.w, fmaf(ahvB, wcB0.w, gb[3]));
            gb[4] = fmaf(ahvA, wcA1.x, fmaf(ahvB, wcB1.x, gb[4]));
            gb[5] = fmaf(ahvA, wcA1.y, fmaf(ahvB, wcB1.y, gb[5]));
            gb[6] = fmaf(ahvA, wcA1.z, fmaf(ahvB, wcB1.z, gb[6]));
            gb[7] = fmaf(ahvA, wcA1.w, fmaf(ahvB, wcB1.w, gb[7]));
        }
    }
    #pragma unroll
    for (int b = 0; b < 8; ++b) gb[b] += __shfl_xor(gb[b], 32, 64);
    if (half == 0) {
        float deg = (float)(r1 - r0);
        float smean = scale_s[0] / (float)N;
        float sc = (logf(deg + 1.f) / smean) / fmaxf(deg, 1.f);
        uint4 u;
        u.x = pk2(gb[0] * sc, gb[1] * sc);
        u.y = pk2(gb[2] * sc, gb[3] * sc);
        u.z = pk2(gb[4] * sc, gb[5] * sc);
        u.w = pk2(gb[6] * sc, gb[7] * sc);
        ((uint4*)g16)[(size_t)n * 32 + o] = u;
    }
}

// ---------------------------------------------------------------------------
// k_final: out = relu(curr + g16 @ Wcat16 + bias). Register-tiled GEMM:
// wave = 4 nodes; lane = (kg 0..7, q 0..7); K split 8-way across kg, g
// chunks held in registers (fully unrolled kk), butterfly reduce over kg.
// ---------------------------------------------------------------------------
__global__ __launch_bounds__(256) void k_final(
        const uint* __restrict__ g16, const __half* __restrict__ Wcat16,
        const float* __restrict__ curr, const float* __restrict__ bias,
        float* __restrict__ out, int N) {
    int t = threadIdx.x;
    int wave = t >> 6, l = t & 63;
    int kg = l >> 3, q = l & 7;
    int nb = blockIdx.x * 16 + wave * 4;
    uint4 gu[4][4];
    #pragma unroll
    for (int nn = 0; nn < 4; ++nn) {
        int n = nb + nn;
        bool v = (n < N);
        #pragma unroll
        for (int c = 0; c < 4; ++c)
            gu[nn][c] = v ? ((const uint4*)g16)[(size_t)n * 32 + kg * 4 + c]
                          : make_uint4(0, 0, 0, 0);
    }
    float4 acc[4];
    #pragma unroll
    for (int nn = 0; nn < 4; ++nn) acc[nn] = make_float4(0.f, 0.f, 0.f, 0.f);
    const ushort* W = (const ushort*)Wcat16;
    #pragma unroll
    for (int kk = 0; kk < 32; ++kk) {
        int k = (kg << 5) + kk;
        uint2 wv = *(const uint2*)(W + k * 32 + q * 4);
        float w0 = c16(wv.x), w1 = c16(wv.x >> 16);
        float w2 = c16(wv.y), w3 = c16(wv.y >> 16);
        #pragma unroll
        for (int nn = 0; nn < 4; ++nn) {
            uint word = ((const uint*)&gu[nn][kk >> 3])[(kk >> 1) & 3];
            float gv = (kk & 1) ? c16(word >> 16) : c16(word);
            acc[nn].x = fmaf(gv, w0, acc[nn].x);
            acc[nn].y = fmaf(gv, w1, acc[nn].y);
            acc[nn].z = fmaf(gv, w2, acc[nn].z);
            acc[nn].w = fmaf(gv, w3, acc[nn].w);
        }
    }
    #pragma unroll
    for (int m = 8; m <= 32; m <<= 1) {
        #pragma unroll
        for (int nn = 0; nn < 4; ++nn) {
            acc[nn].x += __shfl_xor(acc[nn].x, m, 64);
            acc[nn].y += __shfl_xor(acc[nn].y, m, 64);
            acc[nn].z += __shfl_xor(acc[nn].z, m, 64);
            acc[nn].w += __shfl_xor(acc[nn].w, m, 64);
        }
    }
    if (kg < 4) {
        int n = nb + kg;
        if (n < N) {
            float4 a = (kg == 0) ? acc[0] : (kg == 1) ? acc[1]
                     : (kg == 2) ? acc[2] : acc[3];
            float4 cv = *(const float4*)&curr[(size_t)n * 32 + q * 4];
            float4 bv = *(const float4*)&bias[q * 4];
            float4 r;
            r.x = fmaxf(cv.x + a.x + bv.x, 0.f);
            r.y = fmaxf(cv.y + a.y + bv.y, 0.f);
            r.z = fmaxf(cv.z + a.z + bv.z, 0.f);
            r.w = fmaxf(cv.w + a.w + bv.w, 0.f);
            *(float4*)&out[(size_t)n * 32 + q * 4] = r;
        }
    }
}

extern "C" void kernel_launch(void* const* d_in, const int* in_sizes, int n_in,
                              void* d_out, int out_size, void* d_ws, size_t ws_size,
                              hipStream_t stream) {
    const float* h        = (const float*)d_in[0];
    const float* weight   = (const float*)d_in[1];
    const float* w_comp   = (const float*)d_in[2];
    const float* slw      = (const float*)d_in[3];
    const float* bias     = (const float*)d_in[4];
    const float* attn_emb = (const float*)d_in[5];
    const float* A_w      = (const float*)d_in[6];
    const float* A_b      = (const float*)d_in[7];
    const float* B_w      = (const float*)d_in[8];
    const float* B_b      = (const float*)d_in[9];
    const int*   src      = (const int*)d_in[10];
    const int*   dst      = (const int*)d_in[11];
    const int*   et       = (const int*)d_in[12];
    float*       out      = (float*)d_out;

    int N = in_sizes[0] / 32;
    int E = in_sizes[10];
    int nsb = (N + NPB - 1) / NPB;

    char* ws = (char*)d_ws;
    size_t off = 0;
    auto alloc = [&](size_t nbytes) {
        char* p = ws + off;
        off += (nbytes + 63) & ~((size_t)63);
        return p;
    };
    float*  scale_s = (float*) alloc(4);
    size_t zero_bytes = off;                       // scale_s only
    int*    rowptr  = (int*)   alloc((size_t)(N + 1) * 4);
    int*    histT   = (int*)   alloc((size_t)nsb * NPLACE * 4);
    int*    binTot  = (int*)   alloc((size_t)(nsb + 1) * 4);
    float*  relA    = (float*) alloc((size_t)NREL * 32 * 4);
    __half* Wcat16  = (__half*)alloc((size_t)256 * 32 * 2);
    uint*   hcat    = (uint*)  alloc((size_t)N * 32 * 4);
    float*  hA2     = (float*) alloc((size_t)N * 32 * 4);
    float*  curr    = (float*) alloc((size_t)N * 32 * 4);
    int*    tmp     = (int*)   alloc((size_t)E * 4);
    int*    packed  = (int*)   alloc((size_t)E * 4);
    uint*   g16     = (uint*)  alloc((size_t)N * 128 * 4);   // N x 256 fp16
    size_t need = off;

    if (ws_size < need) {
        fprintf(stderr, "kernel_launch: ws too small (%zu < %zu bytes) — no work launched\n",
                ws_size, need);
        return;
    }

    (void)hipMemsetAsync(d_ws, 0, zero_bytes, stream);

    int nb_pre = (N + 31) / 32;
    k_fused1<<<nb_pre + 64 + NPLACE, 256, 0, stream>>>(
        h, A_w, slw, weight, attn_emb, A_b, dst,
        hcat, hA2, curr, Wcat16, relA, histT, N, E, nb_pre);

    k_scanH<<<nsb, NPLACE, 0, stream>>>(histT, binTot);
    k_scanB<<<1, 1024, 0, stream>>>(binTot, nsb);

    k_place<<<NPLACE, 256, 0, stream>>>(src, dst, et, histT, binTot, tmp, N, E);

    k_sortbin<<<nsb, 256, 0, stream>>>(tmp, packed, binTot, rowptr, scale_s, N, E);

    k_node_agg<<<(N + 3) / 4, 256, 0, stream>>>(
        hcat, hA2, relA, w_comp, B_w, B_b, rowptr, packed, scale_s, g16, N);

    k_final<<<(N + 15) / 16, 256, 0, stream>>>(g16, Wcat16, curr, bias, out, N);
}

// Round 12
// 175.468 us; speedup vs baseline: 1.2648x; 1.2648x over previous
//
#include <hip/hip_runtime.h>
#include <hip/hip_fp16.h>
#include <cstdio>
#include <cstdint>

#define NREL 16
#define NBASE 8
#define NPB 512            // nodes per super-bin (bin = dst >> 9)
#define NPLACE 256         // histogram/place blocks
// Record packing: src[16:0] | et[20:17] | dlow[29:21]  (N <= 2^17)

typedef _Float16 half8 __attribute__((ext_vector_type(8)));
typedef float floatx4 __attribute__((ext_vector_type(4)));

// ---------------------------------------------------------------------------
template <int CTRL>
__device__ __forceinline__ float dpp_add_f(float x) {
    int xi = __builtin_bit_cast(int, x);
    int yi = __builtin_amdgcn_update_dpp(0, xi, CTRL, 0xF, 0xF, true);
    return x + __builtin_bit_cast(float, yi);
}

// ---------------------------------------------------------------------------
// k_fused1: three independent jobs, selected by block range:
//   [0, nb_pre)          node_pre (32 nodes/block): hA1(fp16)=h@A_w[0:32],
//                        h16=fp16(h), hA2=h@A_w[32:64], curr=h@slw
//   [nb_pre, +64)        prep: relwB16 (MFMA B-frag layout, R7-verified); relA
//   [nb_pre+64, +NPLACE) hist2: per-(block,super-bin) LDS histogram of dst
// ---------------------------------------------------------------------------
__global__ __launch_bounds__(256) void k_fused1(
        const float* __restrict__ h, const float* __restrict__ A_w,
        const float* __restrict__ slw,
        const float* __restrict__ weight, const float* __restrict__ w_comp,
        const float* __restrict__ attn_emb, const float* __restrict__ A_b,
        const int* __restrict__ dst,
        __half* __restrict__ hA1, _Float16* __restrict__ h16,
        float* __restrict__ hA2, float* __restrict__ curr,
        _Float16* __restrict__ relwB16, float* __restrict__ relA,
        int* __restrict__ histT,
        int N, int E, int nb_pre) {
    __shared__ __align__(16) float Wall[32 * 128];   // [i][c]: c<32 A1, <64 A2, <96 slw
    __shared__ float hbuf[32 * 33];
    __shared__ int hist[256];
    int bx = blockIdx.x;
    int t = threadIdx.x;
    if (bx < nb_pre) {
        // ---- node_pre: 32 nodes per block ----
        #pragma unroll
        for (int k = 0; k < 16; ++k) {
            int idx = t + 256 * k;
            int i = idx >> 7, c = idx & 127;
            float v = 0.f;
            if (c < 32)       v = A_w[i * 32 + c];
            else if (c < 64)  v = A_w[(32 + i) * 32 + (c - 32)];
            else if (c < 96)  v = slw[i * 32 + (c - 64)];
            Wall[idx] = v;
        }
        int n0 = bx * 32;
        #pragma unroll
        for (int k = 0; k < 4; ++k) {
            int idx = t + 256 * k;                   // 0..1023
            int row = idx >> 5, col = idx & 31;
            int n = n0 + row;
            hbuf[row * 33 + col] = (n < N) ? h[n * 32 + col] : 0.f;
        }
        __syncthreads();
        int nl = t >> 3;                             // node 0..31
        int tg = t & 7;                              // col-group 0..7 (12 cols)
        float4 a0 = {0,0,0,0}, a1 = {0,0,0,0}, a2 = {0,0,0,0};
        #pragma unroll 8
        for (int i = 0; i < 32; ++i) {
            float hv = hbuf[nl * 33 + i];
            float4 w0 = *(const float4*)&Wall[i * 128 + tg * 12];
            float4 w1 = *(const float4*)&Wall[i * 128 + tg * 12 + 4];
            float4 w2 = *(const float4*)&Wall[i * 128 + tg * 12 + 8];
            a0.x += hv * w0.x; a0.y += hv * w0.y; a0.z += hv * w0.z; a0.w += hv * w0.w;
            a1.x += hv * w1.x; a1.y += hv * w1.y; a1.z += hv * w1.z; a1.w += hv * w1.w;
            a2.x += hv * w2.x; a2.y += hv * w2.y; a2.z += hv * w2.z; a2.w += hv * w2.w;
        }
        int n = n0 + nl;
        if (n < N) {
            float4 acc[3] = {a0, a1, a2};
            #pragma unroll
            for (int j = 0; j < 3; ++j) {
                int c = tg * 12 + j * 4;
                if (c < 32) {
                    *(__half2*)&hA1[n * 32 + c]     = __floats2half2_rn(acc[j].x, acc[j].y);
                    *(__half2*)&hA1[n * 32 + c + 2] = __floats2half2_rn(acc[j].z, acc[j].w);
                    __half2 p0 = __floats2half2_rn(hbuf[nl * 33 + c], hbuf[nl * 33 + c + 1]);
                    __half2 p1 = __floats2half2_rn(hbuf[nl * 33 + c + 2], hbuf[nl * 33 + c + 3]);
                    *(__half2*)&h16[n * 32 + c]     = p0;
                    *(__half2*)&h16[n * 32 + c + 2] = p1;
                } else if (c < 64) {
                    *(float4*)&hA2[n * 32 + (c - 32)] = acc[j];
                } else {
                    *(float4*)&curr[n * 32 + (c - 64)] = acc[j];
                }
            }
        }
    } else if (bx < nb_pre + 64) {
        // ---- prep: relwB16 in B-frag layout (R7-verified) + relA ----
        int pidx = (bx - nb_pre) * 256 + t;          // 0..16383
        int r = pidx >> 10, rem = pidx & 1023;
        int nb = rem >> 9, lj = rem & 511;
        int l = lj >> 3, j = lj & 7;
        int i = ((l >> 4) << 3) + j;                 // k index
        int o = nb * 16 + (l & 15);                  // n index
        float acc = 0.f;
        #pragma unroll
        for (int b = 0; b < NBASE; ++b)
            acc += w_comp[r * NBASE + b] * weight[b * 1024 + i * 32 + o];
        relwB16[pidx] = (_Float16)acc;
        if (pidx < 512) {
            int rr = pidx >> 5, oo = pidx & 31;
            float a = A_b[oo];
            #pragma unroll 8
            for (int ii = 0; ii < 32; ++ii)
                a += attn_emb[rr * 32 + ii] * A_w[(64 + ii) * 32 + oo];
            relA[pidx] = a;
        }
    } else {
        // ---- hist2 ----
        int nsb = (N + NPB - 1) / NPB;
        hist[t] = 0;
        __syncthreads();
        int blk = bx - (nb_pre + 64);
        int bpb = (E + NPLACE - 1) / NPLACE;
        int e0 = blk * bpb;
        int e1 = e0 + bpb; if (e1 > E) e1 = E;
        for (int e = e0 + t; e < e1; e += 256)
            atomicAdd(&hist[dst[e] >> 9], 1);
        __syncthreads();
        if (t < nsb) histT[t * NPLACE + blk] = hist[t];
    }
}

// ---------------------------------------------------------------------------
// k_scanH: one block per super-bin. Exclusive scan over the bin's NPLACE
// block-counts (in place, bin-LOCAL); bin total -> binTot[bin].
// ---------------------------------------------------------------------------
__global__ __launch_bounds__(NPLACE) void k_scanH(int* __restrict__ histT,
        int* __restrict__ binTot) {
    __shared__ int sd[NPLACE];
    int bin = blockIdx.x, t = threadIdx.x;
    int v = histT[bin * NPLACE + t];
    sd[t] = v;
    __syncthreads();
    for (int off = 1; off < NPLACE; off <<= 1) {
        int x = (t >= off) ? sd[t - off] : 0;
        __syncthreads();
        sd[t] += x;
        __syncthreads();
    }
    histT[bin * NPLACE + t] = sd[t] - v;
    if (t == NPLACE - 1) binTot[bin] = sd[NPLACE - 1];
}

// ---------------------------------------------------------------------------
// k_scanB: single block exclusive-scans binTot in place (chunked);
// binTot[nsb] = total (= E).
// ---------------------------------------------------------------------------
__global__ __launch_bounds__(1024) void k_scanB(int* __restrict__ binTot, int nsb) {
    __shared__ int sd[1024];
    __shared__ int carry;
    int t = threadIdx.x;
    if (t == 0) carry = 0;
    __syncthreads();
    for (int base = 0; base < nsb; base += 1024) {
        int v = (base + t < nsb) ? binTot[base + t] : 0;
        sd[t] = v;
        __syncthreads();
        for (int off = 1; off < 1024; off <<= 1) {
            int x = (t >= off) ? sd[t - off] : 0;
            __syncthreads();
            sd[t] += x;
            __syncthreads();
        }
        int c = carry;
        if (base + t < nsb) binTot[base + t] = sd[t] - v + c;
        int tot = sd[1023];
        __syncthreads();
        if (t == 0) carry = c + tot;
        __syncthreads();
    }
    if (t == 0) binTot[nsb] = carry;
}

// ---------------------------------------------------------------------------
// k_fused2: two independent jobs by block range:
//   [0, nb_hrel)          hrel via MFMA: block = 16-node tile; wave w covers
//                         col-groups w*8..w*8+7 (one mfma_f32_16x16x32_f16
//                         each, B-frags from relwB16, A = 16B coalesced load
//                         from h16). D staged in LDS, written coalesced.
//   [nb_hrel, +NPLACE)    place: LDS cursors, contiguous runs, LDS atomics only.
// ---------------------------------------------------------------------------
__global__ __launch_bounds__(256) void k_fused2(
        const _Float16* __restrict__ h16, const _Float16* __restrict__ relwB16,
        __half* __restrict__ hrel16,
        const int* __restrict__ src, const int* __restrict__ dst,
        const int* __restrict__ et,
        const int* __restrict__ histT, const int* __restrict__ binTot,
        int* __restrict__ tmp,
        int N, int E, int nb_hrel) {
    __shared__ __align__(16) _Float16 tile[16 * 512];   // 16KB
    __shared__ int cur[256];
    int bx = blockIdx.x;
    int t = threadIdx.x;
    if (bx < nb_hrel) {
        // ---- hrel via MFMA ----
        int n0 = bx * 16;
        int l = t & 63, w = t >> 6;
        int ar = n0 + (l & 15);                      // A row = node
        if (ar >= N) ar = N - 1;                     // clamp (stores masked below)
        half8 af = *(const half8*)(h16 + (size_t)ar * 32 + ((l >> 4) << 3));
        #pragma unroll
        for (int gg = 0; gg < 8; ++gg) {
            int g = w * 8 + gg;                      // col-group 0..31
            half8 bf = *(const half8*)(relwB16 + (size_t)g * 512 + l * 8);
            floatx4 d = {0.f, 0.f, 0.f, 0.f};
            d = __builtin_amdgcn_mfma_f32_16x16x32_f16(af, bf, d, 0, 0, 0);
            #pragma unroll
            for (int q = 0; q < 4; ++q) {
                int row = ((l >> 4) << 2) + q;       // D row = node-in-tile
                tile[row * 512 + g * 16 + (l & 15)] = (_Float16)d[q];
            }
        }
        __syncthreads();
        #pragma unroll
        for (int p = 0; p < 4; ++p) {
            int idx = p * 256 + t;                   // 0..1023 chunks of 8 halves
            int row = idx >> 6, c8 = (idx & 63) << 3;
            int n = n0 + row;
            if (n < N)
                *(uint4*)&hrel16[(size_t)n * 512 + c8] = *(const uint4*)&tile[row * 512 + c8];
        }
    } else {
        // ---- place ----
        int nsb = (N + NPB - 1) / NPB;
        int blk = bx - nb_hrel;
        if (t < nsb) cur[t] = histT[t * NPLACE + blk] + binTot[t];
        __syncthreads();
        int bpb = (E + NPLACE - 1) / NPLACE;
        int e0 = blk * bpb;
        int e1 = e0 + bpb; if (e1 > E) e1 = E;
        for (int e = e0 + t; e < e1; e += 256) {
            int d = dst[e];
            int pos = atomicAdd(&cur[d >> 9], 1);
            tmp[pos] = src[e] | (et[e] << 17) | ((d & 511) << 21);
        }
    }
}

// ---------------------------------------------------------------------------
// k_sortbin: one block per super-bin. Counts per-node degrees in LDS,
// block-scans -> writes rowptr + scale_s partial, then places records in
// exact per-node order.
// ---------------------------------------------------------------------------
__global__ __launch_bounds__(256) void k_sortbin(
        const int* __restrict__ tmp, int* __restrict__ packed,
        const int* __restrict__ binTot,
        int* __restrict__ rowptr, float* __restrict__ scale_s,
        int N, int E) {
    __shared__ int cnt[NPB];
    __shared__ int sa[256];
    __shared__ float sf[256];
    int t = threadIdx.x;
    int bin = blockIdx.x;
    int n0 = bin * NPB;
    cnt[t] = 0; cnt[t + 256] = 0;
    __syncthreads();
    int start = binTot[bin], end = binTot[bin + 1];
    for (int i = start + t; i < end; i += 256)
        atomicAdd(&cnt[(tmp[i] >> 21) & 511], 1);
    __syncthreads();
    int c0 = cnt[2 * t], c1 = cnt[2 * t + 1];
    sa[t] = c0 + c1;
    __syncthreads();
    for (int off = 1; off < 256; off <<= 1) {
        int x = (t >= off) ? sa[t - off] : 0;
        __syncthreads();
        sa[t] += x;
        __syncthreads();
    }
    int excl0 = sa[t] - (c0 + c1);
    int excl1 = excl0 + c0;
    int nA = n0 + 2 * t, nB = n0 + 2 * t + 1;
    if (nA <= N) rowptr[nA] = start + excl0;
    if (nB <= N) rowptr[nB] = start + excl1;
    float f = 0.f;
    if (nA < N) f += logf((float)c0 + 1.f);
    if (nB < N) f += logf((float)c1 + 1.f);
    sf[t] = f;
    __syncthreads();
    for (int s2 = 128; s2 > 0; s2 >>= 1) {
        if (t < s2) sf[t] += sf[t + s2];
        __syncthreads();
    }
    if (t == 0) atomicAdd(scale_s, sf[0]);
    cnt[2 * t] = start + excl0;
    cnt[2 * t + 1] = start + excl1;
    __syncthreads();
    for (int i = start + t; i < end; i += 256) {
        int rec = tmp[i];
        int dl = (rec >> 21) & 511;
        int pos = atomicAdd(&cnt[dl], 1);
        packed[pos] = rec;
    }
}

// ---------------------------------------------------------------------------
// k_node_agg: one node per 64-lane wave, 2 edges per step (one per 32-half),
// 2 steps batched (4 edges' gathers in flight). CSR gather from fp16 tables,
// DPP attention reduce, register accumulate, fused epilogue. (R10-verified.)
// ---------------------------------------------------------------------------
__global__ __launch_bounds__(256) void k_node_agg(
        const __half* __restrict__ hrel16, const __half* __restrict__ hA1,
        const float* __restrict__ hA2, const float* __restrict__ relA,
        const float* __restrict__ B_w, const float* __restrict__ B_b,
        const float* __restrict__ curr, const float* __restrict__ bias,
        const int* __restrict__ rowptr,
        const int* __restrict__ packed, const float* __restrict__ scale_s,
        float* __restrict__ out, int N) {
    int t = threadIdx.x;
    int wave = t >> 6, t64 = t & 63;
    int half = t64 >> 5, o = t64 & 31;
    int n = blockIdx.x * 4 + wave;
    if (n >= N) return;
    int r0 = rowptr[n], r1 = rowptr[n + 1];
    float hA2n = hA2[n * 32 + o];
    float bwo = B_w[o];
    float bb  = B_b[0];
    float acc = 0.f;
    for (int c0 = r0; c0 < r1; c0 += 64) {
        int j = c0 + t64;
        int pk = (j < r1) ? packed[j] : 0;
        int m = r1 - c0; if (m > 64) m = 64;
        for (int k = 0; k < m; k += 4) {
            int idxA = k + half;
            int idxB = k + 2 + half;
            int pkA = __shfl(pk, idxA, 64);
            int pkB = __shfl(pk, idxB, 64);
            int sA = pkA & 0x1FFFF, rA = (pkA >> 17) & 15;
            int sB = pkB & 0x1FFFF, rB = (pkB >> 17) & 15;
            float msgA = __half2float(hrel16[(size_t)sA * 512 + (rA << 5) + o]);
            float a1A  = __half2float(hA1[(sA << 5) + o]);
            float msgB = __half2float(hrel16[(size_t)sB * 512 + (rB << 5) + o]);
            float a1B  = __half2float(hA1[(sB << 5) + o]);
            float zA = a1A + hA2n + relA[(rA << 5) + o];
            float zB = a1B + hA2n + relA[(rB << 5) + o];
            float pA = fmaxf(zA, 0.f) * bwo;
            float pB = fmaxf(zB, 0.f) * bwo;
            pA = dpp_add_f<0x111>(pA); pB = dpp_add_f<0x111>(pB);
            pA = dpp_add_f<0x112>(pA); pB = dpp_add_f<0x112>(pB);
            pA = dpp_add_f<0x114>(pA); pB = dpp_add_f<0x114>(pB);
            pA = dpp_add_f<0x118>(pA); pB = dpp_add_f<0x118>(pB);
            pA = dpp_add_f<0x142>(pA); pB = dpp_add_f<0x142>(pB);
            pA = __shfl(pA, 31, 32) + bb;
            pB = __shfl(pB, 31, 32) + bb;
            float aA = 1.f / (1.f + __expf(-pA));
            float aB = 1.f / (1.f + __expf(-pB));
            acc += (idxA < m) ? aA * msgA : 0.f;
            acc += (idxB < m) ? aB * msgB : 0.f;
        }
    }
    acc += __shfl_xor(acc, 32, 64);
    if (half == 0) {
        float deg = (float)(r1 - r0);
        float smean = scale_s[0] / (float)N;
        float scale = logf(deg + 1.0f);
        float v = curr[n * 32 + o] + (scale / smean) * acc / fmaxf(deg, 1.f) + bias[o];
        out[n * 32 + o] = fmaxf(v, 0.f);
    }
}

extern "C" void kernel_launch(void* const* d_in, const int* in_sizes, int n_in,
                              void* d_out, int out_size, void* d_ws, size_t ws_size,
                              hipStream_t stream) {
    const float* h        = (const float*)d_in[0];
    const float* weight   = (const float*)d_in[1];
    const float* w_comp   = (const float*)d_in[2];
    const float* slw      = (const float*)d_in[3];
    const float* bias     = (const float*)d_in[4];
    const float* attn_emb = (const float*)d_in[5];
    const float* A_w      = (const float*)d_in[6];
    const float* A_b      = (const float*)d_in[7];
    const float* B_w      = (const float*)d_in[8];
    const float* B_b      = (const float*)d_in[9];
    const int*   src      = (const int*)d_in[10];
    const int*   dst      = (const int*)d_in[11];
    const int*   et       = (const int*)d_in[12];
    float*       out      = (float*)d_out;

    int N = in_sizes[0] / 32;
    int E = in_sizes[10];
    int nsb = (N + NPB - 1) / NPB;

    char* ws = (char*)d_ws;
    size_t off = 0;
    auto alloc = [&](size_t nbytes) {
        char* p = ws + off;
        off += (nbytes + 63) & ~((size_t)63);
        return p;
    };
    float*     scale_s = (float*)    alloc(4);
    size_t zero_bytes = off;                       // scale_s only
    int*       rowptr  = (int*)      alloc((size_t)(N + 1) * 4);
    int*       histT   = (int*)      alloc((size_t)nsb * NPLACE * 4);
    int*       binTot  = (int*)      alloc((size_t)(nsb + 1) * 4);
    _Float16*  relwB16 = (_Float16*) alloc((size_t)NREL * 1024 * 2);
    float*     relA    = (float*)    alloc((size_t)NREL * 32 * 4);
    __half*    hA1     = (__half*)   alloc((size_t)N * 32 * 2);
    _Float16*  h16     = (_Float16*) alloc((size_t)N * 32 * 2);
    float*     hA2     = (float*)    alloc((size_t)N * 32 * 4);
    float*     curr    = (float*)    alloc((size_t)N * 32 * 4);
    int*       tmp     = (int*)      alloc((size_t)E * 4);
    int*       packed  = (int*)      alloc((size_t)E * 4);
    __half*    hrel16  = (__half*)   alloc((size_t)N * 512 * 2);
    size_t need = off;

    if (ws_size < need) {
        fprintf(stderr, "kernel_launch: ws too small (%zu < %zu bytes) — no work launched\n",
                ws_size, need);
        return;
    }

    (void)hipMemsetAsync(d_ws, 0, zero_bytes, stream);

    int nb_pre = (N + 31) / 32;
    k_fused1<<<nb_pre + 64 + NPLACE, 256, 0, stream>>>(
        h, A_w, slw, weight, w_comp, attn_emb, A_b, dst,
        hA1, h16, hA2, curr, relwB16, relA, histT, N, E, nb_pre);

    k_scanH<<<nsb, NPLACE, 0, stream>>>(histT, binTot);
    k_scanB<<<1, 1024, 0, stream>>>(binTot, nsb);

    int nb_hrel = (N + 15) / 16;
    k_fused2<<<nb_hrel + NPLACE, 256, 0, stream>>>(
        h16, relwB16, hrel16, src, dst, et, histT, binTot, tmp, N, E, nb_hrel);

    k_sortbin<<<nsb, 256, 0, stream>>>(tmp, packed, binTot, rowptr, scale_s, N, E);

    k_node_agg<<<(N + 3) / 4, 256, 0, stream>>>(
        hrel16, hA1, hA2, relA, B_w, B_b, curr, bias,
        rowptr, packed, scale_s, out, N);
}

// Round 13
// 163.065 us; speedup vs baseline: 1.3610x; 1.0761x over previous
//
#include <hip/hip_runtime.h>
#include <hip/hip_fp16.h>
#include <cstdio>
#include <cstdint>

#define NREL 16
#define NBASE 8
#define NPB 512            // nodes per super-bin (bin = dst >> 9)
#define NPLACE 256         // histogram/place blocks
// Record packing: src[16:0] | et[20:17] | dlow[29:21]  (N <= 2^17)

typedef _Float16 half8 __attribute__((ext_vector_type(8)));
typedef float floatx4 __attribute__((ext_vector_type(4)));

// ---------------------------------------------------------------------------
template <int CTRL>
__device__ __forceinline__ float dpp_add_f(float x) {
    int xi = __builtin_bit_cast(int, x);
    int yi = __builtin_amdgcn_update_dpp(0, xi, CTRL, 0xF, 0xF, true);
    return x + __builtin_bit_cast(float, yi);
}

// ---------------------------------------------------------------------------
// k_fused1: two independent jobs, selected by block range:
//   [0, nb_pre)          node_pre via MFMA (64 nodes/block, 16/wave):
//                        A = fp16(h rows) in-register, B-frags built from
//                        L2-hot A_w/slw, 6 mfma_f32_16x16x32_f16 per wave ->
//                        hA1 (fp16), hA2 (f32), curr (f32); h16 = A-frag cvt.
//   [nb_pre, +NPLACE)    hist2: per-(block,super-bin) LDS histogram of dst
// Fragment layouts identical to R12's verified k_fused2 MFMA.
// ---------------------------------------------------------------------------
__global__ __launch_bounds__(256) void k_fused1(
        const float* __restrict__ h, const float* __restrict__ A_w,
        const float* __restrict__ slw,
        const int* __restrict__ dst,
        __half* __restrict__ hA1, _Float16* __restrict__ h16,
        float* __restrict__ hA2, float* __restrict__ curr,
        int* __restrict__ histT,
        int N, int E, int nb_pre) {
    __shared__ int hist[256];
    int bx = blockIdx.x;
    int t = threadIdx.x;
    if (bx < nb_pre) {
        // ---- node_pre via MFMA ----
        int w = t >> 6, l = t & 63;
        int n0 = bx * 64 + w * 16;
        if (n0 >= N) return;
        int lr = l & 15, lg = l >> 4;
        int anode = n0 + lr;
        int arc = (anode < N) ? anode : N - 1;   // clamp; stores masked
        int ac = lg * 8;
        float4 hv0 = *(const float4*)&h[(size_t)arc * 32 + ac];
        float4 hv1 = *(const float4*)&h[(size_t)arc * 32 + ac + 4];
        half8 af;
        af[0] = (_Float16)hv0.x; af[1] = (_Float16)hv0.y;
        af[2] = (_Float16)hv0.z; af[3] = (_Float16)hv0.w;
        af[4] = (_Float16)hv1.x; af[5] = (_Float16)hv1.y;
        af[6] = (_Float16)hv1.z; af[7] = (_Float16)hv1.w;
        if (anode < N)
            *(uint4*)&h16[(size_t)anode * 32 + ac] = *(const uint4*)&af;
        #pragma unroll
        for (int g = 0; g < 6; ++g) {
            half8 bf;
            #pragma unroll
            for (int j = 0; j < 8; ++j) {
                int i = lg * 8 + j;                  // k index (h feature)
                int oc = g * 16 + lr;                // out col 0..95
                float v;
                if (g < 2)      v = A_w[i * 32 + oc];
                else if (g < 4) v = A_w[(32 + i) * 32 + (oc - 32)];
                else            v = slw[i * 32 + (oc - 64)];
                bf[j] = (_Float16)v;
            }
            floatx4 d = {0.f, 0.f, 0.f, 0.f};
            d = __builtin_amdgcn_mfma_f32_16x16x32_f16(af, bf, d, 0, 0, 0);
            #pragma unroll
            for (int q = 0; q < 4; ++q) {
                int node = n0 + lg * 4 + q;          // D row = node
                int oc = g * 16 + lr;                // D col = out col
                if (node < N) {
                    if (g < 2)      hA1[(size_t)node * 32 + oc] = __float2half(d[q]);
                    else if (g < 4) hA2[(size_t)node * 32 + (oc - 32)] = d[q];
                    else            curr[(size_t)node * 32 + (oc - 64)] = d[q];
                }
            }
        }
    } else {
        // ---- hist2 ----
        int nsb = (N + NPB - 1) / NPB;
        hist[t] = 0;
        __syncthreads();
        int blk = bx - nb_pre;
        int bpb = (E + NPLACE - 1) / NPLACE;
        int e0 = blk * bpb;
        int e1 = e0 + bpb; if (e1 > E) e1 = E;
        for (int e = e0 + t; e < e1; e += 256)
            atomicAdd(&hist[dst[e] >> 9], 1);
        __syncthreads();
        if (t < nsb) histT[t * NPLACE + blk] = hist[t];
    }
}

// ---------------------------------------------------------------------------
// k_scanH_prep: two jobs by block range:
//   [0, nsb)      per-super-bin exclusive scan of NPLACE block-counts
//                 (in place, bin-LOCAL); bin total -> binTot[bin].
//   [nsb, +64)    prep: relwB16 (MFMA B-frag layout, R12-verified) + relA.
// ---------------------------------------------------------------------------
__global__ __launch_bounds__(NPLACE) void k_scanH_prep(
        int* __restrict__ histT, int* __restrict__ binTot,
        const float* __restrict__ weight, const float* __restrict__ w_comp,
        const float* __restrict__ attn_emb, const float* __restrict__ A_w,
        const float* __restrict__ A_b,
        _Float16* __restrict__ relwB16, float* __restrict__ relA, int nsb) {
    __shared__ int sd[NPLACE];
    int bx = blockIdx.x, t = threadIdx.x;
    if (bx < nsb) {
        int bin = bx;
        int v = histT[bin * NPLACE + t];
        sd[t] = v;
        __syncthreads();
        for (int off = 1; off < NPLACE; off <<= 1) {
            int x = (t >= off) ? sd[t - off] : 0;
            __syncthreads();
            sd[t] += x;
            __syncthreads();
        }
        histT[bin * NPLACE + t] = sd[t] - v;
        if (t == NPLACE - 1) binTot[bin] = sd[NPLACE - 1];
    } else {
        int pidx = (bx - nsb) * 256 + t;             // 0..16383
        int r = pidx >> 10, rem = pidx & 1023;
        int nb = rem >> 9, lj = rem & 511;
        int l = lj >> 3, j = lj & 7;
        int i = ((l >> 4) << 3) + j;                 // k index
        int o = nb * 16 + (l & 15);                  // n index
        float acc = 0.f;
        #pragma unroll
        for (int b = 0; b < NBASE; ++b)
            acc += w_comp[r * NBASE + b] * weight[b * 1024 + i * 32 + o];
        relwB16[pidx] = (_Float16)acc;
        if (pidx < 512) {
            int rr = pidx >> 5, oo = pidx & 31;
            float a = A_b[oo];
            #pragma unroll 8
            for (int ii = 0; ii < 32; ++ii)
                a += attn_emb[rr * 32 + ii] * A_w[(64 + ii) * 32 + oo];
            relA[pidx] = a;
        }
    }
}

// ---------------------------------------------------------------------------
// k_scanB: single block exclusive-scans binTot in place (chunked);
// binTot[nsb] = total (= E).
// ---------------------------------------------------------------------------
__global__ __launch_bounds__(1024) void k_scanB(int* __restrict__ binTot, int nsb) {
    __shared__ int sd[1024];
    __shared__ int carry;
    int t = threadIdx.x;
    if (t == 0) carry = 0;
    __syncthreads();
    for (int base = 0; base < nsb; base += 1024) {
        int v = (base + t < nsb) ? binTot[base + t] : 0;
        sd[t] = v;
        __syncthreads();
        for (int off = 1; off < 1024; off <<= 1) {
            int x = (t >= off) ? sd[t - off] : 0;
            __syncthreads();
            sd[t] += x;
            __syncthreads();
        }
        int c = carry;
        if (base + t < nsb) binTot[base + t] = sd[t] - v + c;
        int tot = sd[1023];
        __syncthreads();
        if (t == 0) carry = c + tot;
        __syncthreads();
    }
    if (t == 0) binTot[nsb] = carry;
}

// ---------------------------------------------------------------------------
// k_fused2: two independent jobs by block range (R12-verified):
//   [0, nb_hrel)          hrel via MFMA: 16-node tile, wave w covers
//                         col-groups w*8..w*8+7; D staged in LDS, written
//                         coalesced as uint4.
//   [nb_hrel, +NPLACE)    place: LDS cursors, contiguous runs, LDS atomics only.
// ---------------------------------------------------------------------------
__global__ __launch_bounds__(256) void k_fused2(
        const _Float16* __restrict__ h16, const _Float16* __restrict__ relwB16,
        __half* __restrict__ hrel16,
        const int* __restrict__ src, const int* __restrict__ dst,
        const int* __restrict__ et,
        const int* __restrict__ histT, const int* __restrict__ binTot,
        int* __restrict__ tmp,
        int N, int E, int nb_hrel) {
    __shared__ __align__(16) _Float16 tile[16 * 512];   // 16KB
    __shared__ int cur[256];
    int bx = blockIdx.x;
    int t = threadIdx.x;
    if (bx < nb_hrel) {
        int n0 = bx * 16;
        int l = t & 63, w = t >> 6;
        int ar = n0 + (l & 15);
        if (ar >= N) ar = N - 1;
        half8 af = *(const half8*)(h16 + (size_t)ar * 32 + ((l >> 4) << 3));
        #pragma unroll
        for (int gg = 0; gg < 8; ++gg) {
            int g = w * 8 + gg;
            half8 bf = *(const half8*)(relwB16 + (size_t)g * 512 + l * 8);
            floatx4 d = {0.f, 0.f, 0.f, 0.f};
            d = __builtin_amdgcn_mfma_f32_16x16x32_f16(af, bf, d, 0, 0, 0);
            #pragma unroll
            for (int q = 0; q < 4; ++q) {
                int row = ((l >> 4) << 2) + q;
                tile[row * 512 + g * 16 + (l & 15)] = (_Float16)d[q];
            }
        }
        __syncthreads();
        #pragma unroll
        for (int p = 0; p < 4; ++p) {
            int idx = p * 256 + t;
            int row = idx >> 6, c8 = (idx & 63) << 3;
            int n = n0 + row;
            if (n < N)
                *(uint4*)&hrel16[(size_t)n * 512 + c8] = *(const uint4*)&tile[row * 512 + c8];
        }
    } else {
        int nsb = (N + NPB - 1) / NPB;
        int blk = bx - nb_hrel;
        if (t < nsb) cur[t] = histT[t * NPLACE + blk] + binTot[t];
        __syncthreads();
        int bpb = (E + NPLACE - 1) / NPLACE;
        int e0 = blk * bpb;
        int e1 = e0 + bpb; if (e1 > E) e1 = E;
        for (int e = e0 + t; e < e1; e += 256) {
            int d = dst[e];
            int pos = atomicAdd(&cur[d >> 9], 1);
            tmp[pos] = src[e] | (et[e] << 17) | ((d & 511) << 21);
        }
    }
}

// ---------------------------------------------------------------------------
// k_sortbin: one block per super-bin. Counts per-node degrees in LDS,
// block-scans -> writes rowptr + scale_s partial, then places records in
// exact per-node order.
// ---------------------------------------------------------------------------
__global__ __launch_bounds__(256) void k_sortbin(
        const int* __restrict__ tmp, int* __restrict__ packed,
        const int* __restrict__ binTot,
        int* __restrict__ rowptr, float* __restrict__ scale_s,
        int N, int E) {
    __shared__ int cnt[NPB];
    __shared__ int sa[256];
    __shared__ float sf[256];
    int t = threadIdx.x;
    int bin = blockIdx.x;
    int n0 = bin * NPB;
    cnt[t] = 0; cnt[t + 256] = 0;
    __syncthreads();
    int start = binTot[bin], end = binTot[bin + 1];
    for (int i = start + t; i < end; i += 256)
        atomicAdd(&cnt[(tmp[i] >> 21) & 511], 1);
    __syncthreads();
    int c0 = cnt[2 * t], c1 = cnt[2 * t + 1];
    sa[t] = c0 + c1;
    __syncthreads();
    for (int off = 1; off < 256; off <<= 1) {
        int x = (t >= off) ? sa[t - off] : 0;
        __syncthreads();
        sa[t] += x;
        __syncthreads();
    }
    int excl0 = sa[t] - (c0 + c1);
    int excl1 = excl0 + c0;
    int nA = n0 + 2 * t, nB = n0 + 2 * t + 1;
    if (nA <= N) rowptr[nA] = start + excl0;
    if (nB <= N) rowptr[nB] = start + excl1;
    float f = 0.f;
    if (nA < N) f += logf((float)c0 + 1.f);
    if (nB < N) f += logf((float)c1 + 1.f);
    sf[t] = f;
    __syncthreads();
    for (int s2 = 128; s2 > 0; s2 >>= 1) {
        if (t < s2) sf[t] += sf[t + s2];
        __syncthreads();
    }
    if (t == 0) atomicAdd(scale_s, sf[0]);
    cnt[2 * t] = start + excl0;
    cnt[2 * t + 1] = start + excl1;
    __syncthreads();
    for (int i = start + t; i < end; i += 256) {
        int rec = tmp[i];
        int dl = (rec >> 21) & 511;
        int pos = atomicAdd(&cnt[dl], 1);
        packed[pos] = rec;
    }
}

// ---------------------------------------------------------------------------
// k_node_agg: one node per 64-lane wave, 2 edges per step per 32-half,
// 4 steps batched (8 edges' gathers in flight). relA staged in LDS.
// CSR gather from fp16 tables, DPP attention reduce, register accumulate,
// fused epilogue.
// ---------------------------------------------------------------------------
__global__ __launch_bounds__(256) void k_node_agg(
        const __half* __restrict__ hrel16, const __half* __restrict__ hA1,
        const float* __restrict__ hA2, const float* __restrict__ relA,
        const float* __restrict__ B_w, const float* __restrict__ B_b,
        const float* __restrict__ curr, const float* __restrict__ bias,
        const int* __restrict__ rowptr,
        const int* __restrict__ packed, const float* __restrict__ scale_s,
        float* __restrict__ out, int N) {
    __shared__ float relA_l[512];
    int t = threadIdx.x;
    relA_l[t] = relA[t];
    relA_l[t + 256] = relA[t + 256];
    __syncthreads();
    int wave = t >> 6, t64 = t & 63;
    int half = t64 >> 5, o = t64 & 31;
    int n = blockIdx.x * 4 + wave;
    if (n >= N) return;
    int r0 = rowptr[n], r1 = rowptr[n + 1];
    float hA2n = hA2[n * 32 + o];
    float bwo = B_w[o];
    float bb  = B_b[0];
    float acc = 0.f;
    for (int c0 = r0; c0 < r1; c0 += 64) {
        int j = c0 + t64;
        int pk = (j < r1) ? packed[j] : 0;
        int m = r1 - c0; if (m > 64) m = 64;
        for (int k = 0; k < m; k += 8) {
            int iA = k + half, iB = k + 2 + half, iC = k + 4 + half, iD = k + 6 + half;
            int pkA = __shfl(pk, iA, 64);
            int pkB = __shfl(pk, iB, 64);
            int pkC = __shfl(pk, iC, 64);
            int pkD = __shfl(pk, iD, 64);
            int sA = pkA & 0x1FFFF, rA = (pkA >> 17) & 15;
            int sB = pkB & 0x1FFFF, rB = (pkB >> 17) & 15;
            int sC = pkC & 0x1FFFF, rC = (pkC >> 17) & 15;
            int sD = pkD & 0x1FFFF, rD = (pkD >> 17) & 15;
            // issue all 8 gathers before any math
            float msgA = __half2float(hrel16[(size_t)sA * 512 + (rA << 5) + o]);
            float msgB = __half2float(hrel16[(size_t)sB * 512 + (rB << 5) + o]);
            float msgC = __half2float(hrel16[(size_t)sC * 512 + (rC << 5) + o]);
            float msgD = __half2float(hrel16[(size_t)sD * 512 + (rD << 5) + o]);
            float a1A  = __half2float(hA1[(sA << 5) + o]);
            float a1B  = __half2float(hA1[(sB << 5) + o]);
            float a1C  = __half2float(hA1[(sC << 5) + o]);
            float a1D  = __half2float(hA1[(sD << 5) + o]);
            float zA = a1A + hA2n + relA_l[(rA << 5) + o];
            float zB = a1B + hA2n + relA_l[(rB << 5) + o];
            float zC = a1C + hA2n + relA_l[(rC << 5) + o];
            float zD = a1D + hA2n + relA_l[(rD << 5) + o];
            float pA = fmaxf(zA, 0.f) * bwo;
            float pB = fmaxf(zB, 0.f) * bwo;
            float pC = fmaxf(zC, 0.f) * bwo;
            float pD = fmaxf(zD, 0.f) * bwo;
            pA = dpp_add_f<0x111>(pA); pB = dpp_add_f<0x111>(pB);
            pC = dpp_add_f<0x111>(pC); pD = dpp_add_f<0x111>(pD);
            pA = dpp_add_f<0x112>(pA); pB = dpp_add_f<0x112>(pB);
            pC = dpp_add_f<0x112>(pC); pD = dpp_add_f<0x112>(pD);
            pA = dpp_add_f<0x114>(pA); pB = dpp_add_f<0x114>(pB);
            pC = dpp_add_f<0x114>(pC); pD = dpp_add_f<0x114>(pD);
            pA = dpp_add_f<0x118>(pA); pB = dpp_add_f<0x118>(pB);
            pC = dpp_add_f<0x118>(pC); pD = dpp_add_f<0x118>(pD);
            pA = dpp_add_f<0x142>(pA); pB = dpp_add_f<0x142>(pB);
            pC = dpp_add_f<0x142>(pC); pD = dpp_add_f<0x142>(pD);
            pA = __shfl(pA, 31, 32) + bb;
            pB = __shfl(pB, 31, 32) + bb;
            pC = __shfl(pC, 31, 32) + bb;
            pD = __shfl(pD, 31, 32) + bb;
            float aA = 1.f / (1.f + __expf(-pA));
            float aB = 1.f / (1.f + __expf(-pB));
            float aC = 1.f / (1.f + __expf(-pC));
            float aD = 1.f / (1.f + __expf(-pD));
            acc += (iA < m) ? aA * msgA : 0.f;
            acc += (iB < m) ? aB * msgB : 0.f;
            acc += (iC < m) ? aC * msgC : 0.f;
            acc += (iD < m) ? aD * msgD : 0.f;
        }
    }
    acc += __shfl_xor(acc, 32, 64);
    if (half == 0) {
        float deg = (float)(r1 - r0);
        float smean = scale_s[0] / (float)N;
        float scale = logf(deg + 1.0f);
        float v = curr[n * 32 + o] + (scale / smean) * acc / fmaxf(deg, 1.f) + bias[o];
        out[n * 32 + o] = fmaxf(v, 0.f);
    }
}

extern "C" void kernel_launch(void* const* d_in, const int* in_sizes, int n_in,
                              void* d_out, int out_size, void* d_ws, size_t ws_size,
                              hipStream_t stream) {
    const float* h        = (const float*)d_in[0];
    const float* weight   = (const float*)d_in[1];
    const float* w_comp   = (const float*)d_in[2];
    const float* slw      = (const float*)d_in[3];
    const float* bias     = (const float*)d_in[4];
    const float* attn_emb = (const float*)d_in[5];
    const float* A_w      = (const float*)d_in[6];
    const float* A_b      = (const float*)d_in[7];
    const float* B_w      = (const float*)d_in[8];
    const float* B_b      = (const float*)d_in[9];
    const int*   src      = (const int*)d_in[10];
    const int*   dst      = (const int*)d_in[11];
    const int*   et       = (const int*)d_in[12];
    float*       out      = (float*)d_out;

    int N = in_sizes[0] / 32;
    int E = in_sizes[10];
    int nsb = (N + NPB - 1) / NPB;

    char* ws = (char*)d_ws;
    size_t off = 0;
    auto alloc = [&](size_t nbytes) {
        char* p = ws + off;
        off += (nbytes + 63) & ~((size_t)63);
        return p;
    };
    float*     scale_s = (float*)    alloc(4);
    size_t zero_bytes = off;                       // scale_s only
    int*       rowptr  = (int*)      alloc((size_t)(N + 1) * 4);
    int*       histT   = (int*)      alloc((size_t)nsb * NPLACE * 4);
    int*       binTot  = (int*)      alloc((size_t)(nsb + 1) * 4);
    _Float16*  relwB16 = (_Float16*) alloc((size_t)NREL * 1024 * 2);
    float*     relA    = (float*)    alloc((size_t)NREL * 32 * 4);
    __half*    hA1     = (__half*)   alloc((size_t)N * 32 * 2);
    _Float16*  h16     = (_Float16*) alloc((size_t)N * 32 * 2);
    float*     hA2     = (float*)    alloc((size_t)N * 32 * 4);
    float*     curr    = (float*)    alloc((size_t)N * 32 * 4);
    int*       tmp     = (int*)      alloc((size_t)E * 4);
    int*       packed  = (int*)      alloc((size_t)E * 4);
    __half*    hrel16  = (__half*)   alloc((size_t)N * 512 * 2);
    size_t need = off;

    if (ws_size < need) {
        fprintf(stderr, "kernel_launch: ws too small (%zu < %zu bytes) — no work launched\n",
                ws_size, need);
        return;
    }

    (void)hipMemsetAsync(d_ws, 0, zero_bytes, stream);

    int nb_pre = (N + 63) / 64;
    k_fused1<<<nb_pre + NPLACE, 256, 0, stream>>>(
        h, A_w, slw, dst, hA1, h16, hA2, curr, histT, N, E, nb_pre);

    k_scanH_prep<<<nsb + 64, NPLACE, 0, stream>>>(
        histT, binTot, weight, w_comp, attn_emb, A_w, A_b, relwB16, relA, nsb);
    k_scanB<<<1, 1024, 0, stream>>>(binTot, nsb);

    int nb_hrel = (N + 15) / 16;
    k_fused2<<<nb_hrel + NPLACE, 256, 0, stream>>>(
        h16, relwB16, hrel16, src, dst, et, histT, binTot, tmp, N, E, nb_hrel);

    k_sortbin<<<nsb, 256, 0, stream>>>(tmp, packed, binTot, rowptr, scale_s, N, E);

    k_node_agg<<<(N + 3) / 4, 256, 0, stream>>>(
        hrel16, hA1, hA2, relA, B_w, B_b, curr, bias,
        rowptr, packed, scale_s, out, N);
}

// Round 14
// 154.575 us; speedup vs baseline: 1.4357x; 1.0549x over previous
//
#include <hip/hip_runtime.h>
#include <hip/hip_fp16.h>
#include <cstdio>
#include <cstdint>

#define NREL 16
#define NBASE 8
#define NPB 512            // nodes per super-bin (bin = dst >> 9)
#define NPLACE 256         // histogram/place blocks
// Record packing: src[16:0] | et[20:17] | dlow[29:21]  (N <= 2^17)

typedef _Float16 half8 __attribute__((ext_vector_type(8)));
typedef float floatx4 __attribute__((ext_vector_type(4)));

// ---------------------------------------------------------------------------
template <int CTRL>
__device__ __forceinline__ float dpp_add_f(float x) {
    int xi = __builtin_bit_cast(int, x);
    int yi = __builtin_amdgcn_update_dpp(0, xi, CTRL, 0xF, 0xF, true);
    return x + __builtin_bit_cast(float, yi);
}

// ---------------------------------------------------------------------------
// k_fused1: two independent jobs, selected by block range:
//   [0, nb_pre)          node_pre via MFMA (64 nodes/block, 16/wave):
//                        hA1 (fp16), hA2 (f32), curr (f32), h16 (A-frag cvt)
//   [nb_pre, +NPLACE)    hist2: per-(block,super-bin) LDS histogram of dst
// ---------------------------------------------------------------------------
__global__ __launch_bounds__(256) void k_fused1(
        const float* __restrict__ h, const float* __restrict__ A_w,
        const float* __restrict__ slw,
        const int* __restrict__ dst,
        __half* __restrict__ hA1, _Float16* __restrict__ h16,
        float* __restrict__ hA2, float* __restrict__ curr,
        int* __restrict__ histT,
        int N, int E, int nb_pre) {
    __shared__ int hist[256];
    int bx = blockIdx.x;
    int t = threadIdx.x;
    if (bx < nb_pre) {
        // ---- node_pre via MFMA ----
        int w = t >> 6, l = t & 63;
        int n0 = bx * 64 + w * 16;
        if (n0 >= N) return;
        int lr = l & 15, lg = l >> 4;
        int anode = n0 + lr;
        int arc = (anode < N) ? anode : N - 1;   // clamp; stores masked
        int ac = lg * 8;
        float4 hv0 = *(const float4*)&h[(size_t)arc * 32 + ac];
        float4 hv1 = *(const float4*)&h[(size_t)arc * 32 + ac + 4];
        half8 af;
        af[0] = (_Float16)hv0.x; af[1] = (_Float16)hv0.y;
        af[2] = (_Float16)hv0.z; af[3] = (_Float16)hv0.w;
        af[4] = (_Float16)hv1.x; af[5] = (_Float16)hv1.y;
        af[6] = (_Float16)hv1.z; af[7] = (_Float16)hv1.w;
        if (anode < N)
            *(uint4*)&h16[(size_t)anode * 32 + ac] = *(const uint4*)&af;
        #pragma unroll
        for (int g = 0; g < 6; ++g) {
            half8 bf;
            #pragma unroll
            for (int j = 0; j < 8; ++j) {
                int i = lg * 8 + j;                  // k index (h feature)
                int oc = g * 16 + lr;                // out col 0..95
                float v;
                if (g < 2)      v = A_w[i * 32 + oc];
                else if (g < 4) v = A_w[(32 + i) * 32 + (oc - 32)];
                else            v = slw[i * 32 + (oc - 64)];
                bf[j] = (_Float16)v;
            }
            floatx4 d = {0.f, 0.f, 0.f, 0.f};
            d = __builtin_amdgcn_mfma_f32_16x16x32_f16(af, bf, d, 0, 0, 0);
            #pragma unroll
            for (int q = 0; q < 4; ++q) {
                int node = n0 + lg * 4 + q;          // D row = node
                int oc = g * 16 + lr;                // D col = out col
                if (node < N) {
                    if (g < 2)      hA1[(size_t)node * 32 + oc] = __float2half(d[q]);
                    else if (g < 4) hA2[(size_t)node * 32 + (oc - 32)] = d[q];
                    else            curr[(size_t)node * 32 + (oc - 64)] = d[q];
                }
            }
        }
    } else {
        // ---- hist2 ----
        int nsb = (N + NPB - 1) / NPB;
        hist[t] = 0;
        __syncthreads();
        int blk = bx - nb_pre;
        int bpb = (E + NPLACE - 1) / NPLACE;
        int e0 = blk * bpb;
        int e1 = e0 + bpb; if (e1 > E) e1 = E;
        for (int e = e0 + t; e < e1; e += 256)
            atomicAdd(&hist[dst[e] >> 9], 1);
        __syncthreads();
        if (t < nsb) histT[t * NPLACE + blk] = hist[t];
    }
}

// ---------------------------------------------------------------------------
// k_scanH_prep: two jobs by block range:
//   [0, nsb)      per-super-bin exclusive scan of NPLACE block-counts
//                 (in place, bin-LOCAL); bin RAW total -> binTot[bin].
//   [nsb, +64)    prep: relwB16 (MFMA B-frag layout) + relA.
// ---------------------------------------------------------------------------
__global__ __launch_bounds__(NPLACE) void k_scanH_prep(
        int* __restrict__ histT, int* __restrict__ binTot,
        const float* __restrict__ weight, const float* __restrict__ w_comp,
        const float* __restrict__ attn_emb, const float* __restrict__ A_w,
        const float* __restrict__ A_b,
        _Float16* __restrict__ relwB16, float* __restrict__ relA, int nsb) {
    __shared__ int sd[NPLACE];
    int bx = blockIdx.x, t = threadIdx.x;
    if (bx < nsb) {
        int bin = bx;
        int v = histT[bin * NPLACE + t];
        sd[t] = v;
        __syncthreads();
        for (int off = 1; off < NPLACE; off <<= 1) {
            int x = (t >= off) ? sd[t - off] : 0;
            __syncthreads();
            sd[t] += x;
            __syncthreads();
        }
        histT[bin * NPLACE + t] = sd[t] - v;
        if (t == NPLACE - 1) binTot[bin] = sd[NPLACE - 1];
    } else {
        int pidx = (bx - nsb) * 256 + t;             // 0..16383
        int r = pidx >> 10, rem = pidx & 1023;
        int nb = rem >> 9, lj = rem & 511;
        int l = lj >> 3, j = lj & 7;
        int i = ((l >> 4) << 3) + j;                 // k index
        int o = nb * 16 + (l & 15);                  // n index
        float acc = 0.f;
        #pragma unroll
        for (int b = 0; b < NBASE; ++b)
            acc += w_comp[r * NBASE + b] * weight[b * 1024 + i * 32 + o];
        relwB16[pidx] = (_Float16)acc;
        if (pidx < 512) {
            int rr = pidx >> 5, oo = pidx & 31;
            float a = A_b[oo];
            #pragma unroll 8
            for (int ii = 0; ii < 32; ++ii)
                a += attn_emb[rr * 32 + ii] * A_w[(64 + ii) * 32 + oo];
            relA[pidx] = a;
        }
    }
}

// ---------------------------------------------------------------------------
// k_fused2: two independent jobs by block range:
//   [0, nb_hrel)          hrel via MFMA: 16-node tile, wave w covers
//                         col-groups w*8..w*8+7; D staged in LDS, written
//                         coalesced as uint4.
//   [nb_hrel, +NPLACE)    place: local scan of raw binTot -> absolute bases;
//                         LDS cursors, contiguous runs, LDS atomics only.
// ---------------------------------------------------------------------------
__global__ __launch_bounds__(256) void k_fused2(
        const _Float16* __restrict__ h16, const _Float16* __restrict__ relwB16,
        __half* __restrict__ hrel16,
        const int* __restrict__ src, const int* __restrict__ dst,
        const int* __restrict__ et,
        const int* __restrict__ histT, const int* __restrict__ binTot,
        int* __restrict__ tmp,
        int N, int E, int nb_hrel) {
    __shared__ __align__(16) _Float16 tile[16 * 512];   // 16KB
    __shared__ int cur[256];
    __shared__ int sd[256];
    int bx = blockIdx.x;
    int t = threadIdx.x;
    if (bx < nb_hrel) {
        int n0 = bx * 16;
        int l = t & 63, w = t >> 6;
        int ar = n0 + (l & 15);
        if (ar >= N) ar = N - 1;
        half8 af = *(const half8*)(h16 + (size_t)ar * 32 + ((l >> 4) << 3));
        #pragma unroll
        for (int gg = 0; gg < 8; ++gg) {
            int g = w * 8 + gg;
            half8 bf = *(const half8*)(relwB16 + (size_t)g * 512 + l * 8);
            floatx4 d = {0.f, 0.f, 0.f, 0.f};
            d = __builtin_amdgcn_mfma_f32_16x16x32_f16(af, bf, d, 0, 0, 0);
            #pragma unroll
            for (int q = 0; q < 4; ++q) {
                int row = ((l >> 4) << 2) + q;
                tile[row * 512 + g * 16 + (l & 15)] = (_Float16)d[q];
            }
        }
        __syncthreads();
        #pragma unroll
        for (int p = 0; p < 4; ++p) {
            int idx = p * 256 + t;
            int row = idx >> 6, c8 = (idx & 63) << 3;
            int n = n0 + row;
            if (n < N)
                *(uint4*)&hrel16[(size_t)n * 512 + c8] = *(const uint4*)&tile[row * 512 + c8];
        }
    } else {
        int nsb = (N + NPB - 1) / NPB;
        int blk = bx - nb_hrel;
        // local exclusive scan of RAW binTot
        int v = (t < nsb) ? binTot[t] : 0;
        sd[t] = v;
        __syncthreads();
        for (int off = 1; off < 256; off <<= 1) {
            int x = (t >= off) ? sd[t - off] : 0;
            __syncthreads();
            sd[t] += x;
            __syncthreads();
        }
        if (t < nsb) cur[t] = histT[t * NPLACE + blk] + sd[t] - v;
        __syncthreads();
        int bpb = (E + NPLACE - 1) / NPLACE;
        int e0 = blk * bpb;
        int e1 = e0 + bpb; if (e1 > E) e1 = E;
        for (int e = e0 + t; e < e1; e += 256) {
            int d = dst[e];
            int pos = atomicAdd(&cur[d >> 9], 1);
            tmp[pos] = src[e] | (et[e] << 17) | ((d & 511) << 21);
        }
    }
}

// ---------------------------------------------------------------------------
// k_sortbin: one 1024-thread block per super-bin (4x the per-block rate of
// the 256-thread version). Local scan of raw binTot -> [start,end); counts
// per-node degrees in LDS, scans -> rowptr + scale_s partial, then places
// records in exact per-node order.
// ---------------------------------------------------------------------------
__global__ __launch_bounds__(1024) void k_sortbin(
        const int* __restrict__ tmp, int* __restrict__ packed,
        const int* __restrict__ binTot,
        int* __restrict__ rowptr, float* __restrict__ scale_s,
        int N, int E, int nsb) {
    __shared__ int cnt[NPB];
    __shared__ int sd[NPB];
    __shared__ float sf[1024];
    __shared__ int sstart, send;
    int t = threadIdx.x;
    int bin = blockIdx.x;
    int n0 = bin * NPB;
    if (t < NPB) cnt[t] = 0;
    // --- local scan of raw binTot -> [start,end) ---
    if (t < 256) sd[t] = (t < nsb) ? binTot[t] : 0;
    __syncthreads();
    for (int off = 1; off < 256; off <<= 1) {
        int x = (t < 256 && t >= off) ? sd[t - off] : 0;
        __syncthreads();
        if (t < 256) sd[t] += x;
        __syncthreads();
    }
    if (t == 0) {
        send = sd[bin];
        sstart = (bin == 0) ? 0 : sd[bin - 1];
    }
    __syncthreads();
    int start = sstart, end = send;
    // --- pass 1: per-node counts ---
    for (int i = start + t; i < end; i += 1024)
        atomicAdd(&cnt[(tmp[i] >> 21) & 511], 1);
    __syncthreads();
    // --- scan the 512 counts (inclusive into sd) ---
    if (t < NPB) sd[t] = cnt[t];
    __syncthreads();
    for (int off = 1; off < NPB; off <<= 1) {
        int x = (t < NPB && t >= off) ? sd[t - off] : 0;
        __syncthreads();
        if (t < NPB) sd[t] += x;
        __syncthreads();
    }
    float f = 0.f;
    if (t < NPB) {
        int node = n0 + t;
        int excl = sd[t] - cnt[t];
        if (node <= N) rowptr[node] = start + excl;
        if (node < N) f = logf((float)cnt[t] + 1.f);
    }
    if (t == 0 && bin == nsb - 1 && (N % NPB) == 0) rowptr[N] = end;
    sf[t] = f;
    __syncthreads();
    for (int s2 = 512; s2 > 0; s2 >>= 1) {
        if (t < s2) sf[t] += sf[t + s2];
        __syncthreads();
    }
    if (t == 0) atomicAdd(scale_s, sf[0]);
    // --- seed cursors ---
    if (t < NPB) cnt[t] = start + sd[t] - cnt[t];
    __syncthreads();
    // --- pass 2: place ---
    for (int i = start + t; i < end; i += 1024) {
        int rec = tmp[i];
        int pos = atomicAdd(&cnt[(rec >> 21) & 511], 1);
        packed[pos] = rec;
    }
}

// ---------------------------------------------------------------------------
// k_node_agg: one node per 64-lane wave, 2 edges per step (one per 32-half),
// 2 steps batched (4 edges' gathers in flight). CSR gather from fp16 tables,
// DPP attention reduce, register accumulate, fused epilogue. (R12-verified
// fastest variant: 4-deep, relA from global.)
// ---------------------------------------------------------------------------
__global__ __launch_bounds__(256) void k_node_agg(
        const __half* __restrict__ hrel16, const __half* __restrict__ hA1,
        const float* __restrict__ hA2, const float* __restrict__ relA,
        const float* __restrict__ B_w, const float* __restrict__ B_b,
        const float* __restrict__ curr, const float* __restrict__ bias,
        const int* __restrict__ rowptr,
        const int* __restrict__ packed, const float* __restrict__ scale_s,
        float* __restrict__ out, int N) {
    int t = threadIdx.x;
    int wave = t >> 6, t64 = t & 63;
    int half = t64 >> 5, o = t64 & 31;
    int n = blockIdx.x * 4 + wave;
    if (n >= N) return;
    int r0 = rowptr[n], r1 = rowptr[n + 1];
    float hA2n = hA2[n * 32 + o];
    float bwo = B_w[o];
    float bb  = B_b[0];
    float acc = 0.f;
    for (int c0 = r0; c0 < r1; c0 += 64) {
        int j = c0 + t64;
        int pk = (j < r1) ? packed[j] : 0;
        int m = r1 - c0; if (m > 64) m = 64;
        for (int k = 0; k < m; k += 4) {
            int idxA = k + half;
            int idxB = k + 2 + half;
            int pkA = __shfl(pk, idxA, 64);
            int pkB = __shfl(pk, idxB, 64);
            int sA = pkA & 0x1FFFF, rA = (pkA >> 17) & 15;
            int sB = pkB & 0x1FFFF, rB = (pkB >> 17) & 15;
            float msgA = __half2float(hrel16[(size_t)sA * 512 + (rA << 5) + o]);
            float a1A  = __half2float(hA1[(sA << 5) + o]);
            float msgB = __half2float(hrel16[(size_t)sB * 512 + (rB << 5) + o]);
            float a1B  = __half2float(hA1[(sB << 5) + o]);
            float zA = a1A + hA2n + relA[(rA << 5) + o];
            float zB = a1B + hA2n + relA[(rB << 5) + o];
            float pA = fmaxf(zA, 0.f) * bwo;
            float pB = fmaxf(zB, 0.f) * bwo;
            pA = dpp_add_f<0x111>(pA); pB = dpp_add_f<0x111>(pB);
            pA = dpp_add_f<0x112>(pA); pB = dpp_add_f<0x112>(pB);
            pA = dpp_add_f<0x114>(pA); pB = dpp_add_f<0x114>(pB);
            pA = dpp_add_f<0x118>(pA); pB = dpp_add_f<0x118>(pB);
            pA = dpp_add_f<0x142>(pA); pB = dpp_add_f<0x142>(pB);
            pA = __shfl(pA, 31, 32) + bb;
            pB = __shfl(pB, 31, 32) + bb;
            float aA = 1.f / (1.f + __expf(-pA));
            float aB = 1.f / (1.f + __expf(-pB));
            acc += (idxA < m) ? aA * msgA : 0.f;
            acc += (idxB < m) ? aB * msgB : 0.f;
        }
    }
    acc += __shfl_xor(acc, 32, 64);
    if (half == 0) {
        float deg = (float)(r1 - r0);
        float smean = scale_s[0] / (float)N;
        float scale = logf(deg + 1.0f);
        float v = curr[n * 32 + o] + (scale / smean) * acc / fmaxf(deg, 1.f) + bias[o];
        out[n * 32 + o] = fmaxf(v, 0.f);
    }
}

extern "C" void kernel_launch(void* const* d_in, const int* in_sizes, int n_in,
                              void* d_out, int out_size, void* d_ws, size_t ws_size,
                              hipStream_t stream) {
    const float* h        = (const float*)d_in[0];
    const float* weight   = (const float*)d_in[1];
    const float* w_comp   = (const float*)d_in[2];
    const float* slw      = (const float*)d_in[3];
    const float* bias     = (const float*)d_in[4];
    const float* attn_emb = (const float*)d_in[5];
    const float* A_w      = (const float*)d_in[6];
    const float* A_b      = (const float*)d_in[7];
    const float* B_w      = (const float*)d_in[8];
    const float* B_b      = (const float*)d_in[9];
    const int*   src      = (const int*)d_in[10];
    const int*   dst      = (const int*)d_in[11];
    const int*   et       = (const int*)d_in[12];
    float*       out      = (float*)d_out;

    int N = in_sizes[0] / 32;
    int E = in_sizes[10];
    int nsb = (N + NPB - 1) / NPB;

    char* ws = (char*)d_ws;
    size_t off = 0;
    auto alloc = [&](size_t nbytes) {
        char* p = ws + off;
        off += (nbytes + 63) & ~((size_t)63);
        return p;
    };
    float*     scale_s = (float*)    alloc(4);
    size_t zero_bytes = off;                       // scale_s only
    int*       rowptr  = (int*)      alloc((size_t)(N + 1) * 4);
    int*       histT   = (int*)      alloc((size_t)nsb * NPLACE * 4);
    int*       binTot  = (int*)      alloc((size_t)(nsb + 1) * 4);
    _Float16*  relwB16 = (_Float16*) alloc((size_t)NREL * 1024 * 2);
    float*     relA    = (float*)    alloc((size_t)NREL * 32 * 4);
    __half*    hA1     = (__half*)   alloc((size_t)N * 32 * 2);
    _Float16*  h16     = (_Float16*) alloc((size_t)N * 32 * 2);
    float*     hA2     = (float*)    alloc((size_t)N * 32 * 4);
    float*     curr    = (float*)    alloc((size_t)N * 32 * 4);
    int*       tmp     = (int*)      alloc((size_t)E * 4);
    int*       packed  = (int*)      alloc((size_t)E * 4);
    __half*    hrel16  = (__half*)   alloc((size_t)N * 512 * 2);
    size_t need = off;

    if (ws_size < need) {
        fprintf(stderr, "kernel_launch: ws too small (%zu < %zu bytes) — no work launched\n",
                ws_size, need);
        return;
    }

    (void)hipMemsetAsync(d_ws, 0, zero_bytes, stream);

    int nb_pre = (N + 63) / 64;
    k_fused1<<<nb_pre + NPLACE, 256, 0, stream>>>(
        h, A_w, slw, dst, hA1, h16, hA2, curr, histT, N, E, nb_pre);

    k_scanH_prep<<<nsb + 64, NPLACE, 0, stream>>>(
        histT, binTot, weight, w_comp, attn_emb, A_w, A_b, relwB16, relA, nsb);

    int nb_hrel = (N + 15) / 16;
    k_fused2<<<nb_hrel + NPLACE, 256, 0, stream>>>(
        h16, relwB16, hrel16, src, dst, et, histT, binTot, tmp, N, E, nb_hrel);

    k_sortbin<<<nsb, 1024, 0, stream>>>(tmp, packed, binTot, rowptr, scale_s, N, E, nsb);

    k_node_agg<<<(N + 3) / 4, 256, 0, stream>>>(
        hrel16, hA1, hA2, relA, B_w, B_b, curr, bias,
        rowptr, packed, scale_s, out, N);
}